// Round 15
// baseline (248.468 us; speedup 1.0000x reference)
//
#include <hip/hip_runtime.h>
#include <hip/hip_fp16.h>
#include <math.h>

#if __has_builtin(__builtin_amdgcn_cvt_pk_f32_fp8) && __has_builtin(__builtin_amdgcn_cvt_pk_fp8_f32)
#define HAS_FP8_CVT 1
#else
#include <hip/hip_fp8.h>
#endif

#define NNODES 100000
#define NEDGES 1600000
#define DIM 128
#define NG 64
#define GATE 512
#define SCAN_NB 98  // ceil(NNODES / 1024)
#define FILL_NPASS 4
#define BUCKET ((NNODES + FILL_NPASS - 1) / FILL_NPASS)  // 25000

// degree histogram / counting-sort offsets
#define HG 128           // edge chunks (12500 edges each)
#define HW 25024         // u32 words per partial (4 packed u8 cols each)
#define HSMEM (HW * 4)   // 100096 B dynamic LDS for k_deghist

// k_lstmm dynamic LDS: xg staged f32 + h double-buffer + h history
#define XL_XG   131072                        // 64*512*4
#define XL_AUX  (512 + 16384)                 // h2h[2][128] half + hsh[64][128] half
#define XL_SMEM (XL_XG + XL_AUX)              // 147968 <= 160K

typedef _Float16 half8_t __attribute__((ext_vector_type(8)));
typedef float f32x4 __attribute__((ext_vector_type(4)));
typedef float f32x2_t __attribute__((ext_vector_type(2)));

// fp8 e4m3 HW converters (encode/decode self-consistent on gfx950)
__device__ __forceinline__ unsigned char f32_to_fp8(float v) {
#ifdef HAS_FP8_CVT
    return (unsigned char)(__builtin_amdgcn_cvt_pk_fp8_f32(v, v, 0, false) & 0xFF);
#else
    __hip_fp8_e4m3 h(v); return h.__x;
#endif
}
__device__ __forceinline__ void fp8x4_acc(unsigned w, float* acc) {
#ifdef HAS_FP8_CVT
    f32x2_t lo = __builtin_amdgcn_cvt_pk_f32_fp8((int)w, false);
    f32x2_t hi = __builtin_amdgcn_cvt_pk_f32_fp8((int)w, true);
    acc[0] += lo[0]; acc[1] += lo[1]; acc[2] += hi[0]; acc[3] += hi[1];
#else
    __hip_fp8_e4m3 h;
#pragma unroll
    for (int q = 0; q < 4; ++q) { h.__x = (w >> (8 * q)) & 0xFF; acc[q] += (float)h; }
#endif
}

// fast sigmoid/tanh: v_exp_f32 + v_rcp_f32 (absmax headroom is ~100x)
__device__ __forceinline__ float sigf(float x) {
    return __builtin_amdgcn_rcpf(1.0f + __expf(-x));
}
__device__ __forceinline__ float tanhfast(float x) {
    float e = __expf(2.0f * x);
    return 1.0f - 2.0f * __builtin_amdgcn_rcpf(e + 1.0f);
}

// ---- degree: per-edge-chunk LDS u8-packed histogram, NO global atomics ----
__global__ __launch_bounds__(1024) void k_deghist(const int* __restrict__ ei, unsigned* __restrict__ partial) {
    extern __shared__ unsigned hist[];  // HW words
    int tid = threadIdx.x;
    for (int i = tid; i < HW; i += 1024) hist[i] = 0u;
    __syncthreads();
    int e0 = blockIdx.x * (NEDGES / HG);
    int e1 = e0 + (NEDGES / HG);
    for (int e = e0 + tid; e < e1; e += 1024) {
        int col = ei[NEDGES + e];
        atomicAdd(&hist[col >> 2], 1u << ((col & 3) * 8));
    }
    __syncthreads();
    unsigned* dst = partial + (size_t)blockIdx.x * HW;
    for (int i = tid; i < HW; i += 1024) dst[i] = hist[i];
}

// fallback if 100KB dynamic LDS unavailable: plain atomic count
__global__ __launch_bounds__(256) void k_deg(const int* __restrict__ ei, int* __restrict__ deg) {
    int e = blockIdx.x * 256 + threadIdx.x;
    if (e < NEDGES) atomicAdd(&deg[ei[NEDGES + e]], 1);
}

// sum HG partials -> deg + dinv, and emit per-chunk exclusive prefix pre8
__global__ __launch_bounds__(256) void k_degred2(const unsigned* __restrict__ partial, unsigned* __restrict__ pre8,
                                                 int* __restrict__ deg, float* __restrict__ dinv) {
    int w = blockIdx.x * 256 + threadIdx.x;  // packed word = 4 cols
    if (w >= NNODES / 4) return;
    unsigned s = 0;
    for (int b = 0; b < HG; ++b) {
        pre8[(size_t)b * HW + w] = s;        // exclusive prefix before chunk b
        s += partial[(size_t)b * HW + w];
    }
    int4 d;
    d.x = s & 255; d.y = (s >> 8) & 255; d.z = (s >> 16) & 255; d.w = (int)(s >> 24);
    ((int4*)deg)[w] = d;
    float4 dv;
    dv.x = rsqrtf((float)d.x + 1.f);
    dv.y = rsqrtf((float)d.y + 1.f);
    dv.z = rsqrtf((float)d.z + 1.f);
    dv.w = rsqrtf((float)d.w + 1.f);
    ((float4*)dinv)[w] = dv;
}

// dinv for the atomic fallback path
__global__ __launch_bounds__(256) void k_dinv(const int* __restrict__ deg, float* __restrict__ dinv) {
    int n = blockIdx.x * 256 + threadIdx.x;
    if (n < NNODES) dinv[n] = rsqrtf((float)deg[n] + 1.0f);
}

// stage 1: per-block exclusive scan of deg; block sums out
__global__ __launch_bounds__(1024) void k_scan1(const int* __restrict__ deg, int* __restrict__ row_ptr,
                                                int* __restrict__ bsum) {
    __shared__ int ls[1024];
    int tid = threadIdx.x;
    int n = blockIdx.x * 1024 + tid;
    int v = (n < NNODES) ? deg[n] : 0;
    ls[tid] = v;
    __syncthreads();
    for (int off = 1; off < 1024; off <<= 1) {
        int t = (tid >= off) ? ls[tid - off] : 0;
        __syncthreads();
        ls[tid] += t;
        __syncthreads();
    }
    if (n < NNODES) row_ptr[n] = ls[tid] - v;  // exclusive within block
    if (tid == 1023) bsum[blockIdx.x] = ls[1023];
}

// stage 2: exclusive scan of block sums + graph segment bounds (batch sorted)
__global__ __launch_bounds__(128) void k_scan2(int* __restrict__ bsum, int* __restrict__ row_ptr,
                                               const int* __restrict__ batch, int* __restrict__ start) {
    __shared__ int ls[128];
    int tid = threadIdx.x;
    int v = (tid < SCAN_NB) ? bsum[tid] : 0;
    ls[tid] = v;
    __syncthreads();
    for (int off = 1; off < 128; off <<= 1) {
        int t = (tid >= off) ? ls[tid - off] : 0;
        __syncthreads();
        ls[tid] += t;
        __syncthreads();
    }
    if (tid < SCAN_NB) bsum[tid] = ls[tid] - v;  // exclusive block offsets
    if (tid == 127) row_ptr[NNODES] = ls[127];
    if (tid <= NG) {
        int lo = 0, hi = NNODES;
        while (lo < hi) {
            int mid = (lo + hi) >> 1;
            if (batch[mid] < tid) lo = mid + 1; else hi = mid;
        }
        start[tid] = lo;
    }
}

// stage 3: add block offsets; init cursor = row_ptr (cursor used by fallback fill only)
__global__ __launch_bounds__(1024) void k_scan3(int* __restrict__ row_ptr, const int* __restrict__ bsum,
                                                int* __restrict__ cursor) {
    int n = blockIdx.x * 1024 + threadIdx.x;
    if (n < NNODES) {
        int rp = row_ptr[n] + bsum[blockIdx.x];
        row_ptr[n] = rp;
        cursor[n] = rp;
    }
}

// Atomic-free CSR fill (counting sort): slot = row_ptr + chunk prefix + LDS local
__global__ __launch_bounds__(1024) void k_fill2(const int* __restrict__ ei, const int* __restrict__ row_ptr,
                                                const unsigned* __restrict__ pre8, int* __restrict__ adj, int b0) {
    __shared__ unsigned lh[BUCKET / 4];  // 25 KB
    int tid = threadIdx.x;
    for (int i = tid; i < BUCKET / 4; i += 1024) lh[i] = 0u;
    __syncthreads();
    const unsigned* myPre = pre8 + (size_t)blockIdx.x * HW;
    int e0 = blockIdx.x * (NEDGES / HG);
    int e1 = e0 + (NEDGES / HG);
    for (int e = e0 + tid; e < e1; e += 1024) {
        int col = ei[NEDGES + e];
        if (col >= b0 && col < b0 + BUCKET) {
            int row = ei[e];
            int lc = col - b0;
            unsigned old = atomicAdd(&lh[lc >> 2], 1u << ((lc & 3) * 8));
            int local = (old >> ((lc & 3) * 8)) & 0xFF;
            int base = row_ptr[col] + (int)((myPre[col >> 2] >> ((col & 3) * 8)) & 0xFF);
            adj[base + local] = row;
        }
    }
}

// fallback: cursor-based fill with temporal bucketing
__global__ __launch_bounds__(256) void k_fillb(const int* __restrict__ ei, int* __restrict__ cursor,
                                               int* __restrict__ adj, int b0) {
    int e = blockIdx.x * 256 + threadIdx.x;
    if (e < NEDGES) {
        int col = ei[NEDGES + e];
        if (col >= b0 && col < b0 + BUCKET) {
            int row = ei[e];
            int pos = atomicAdd(&cursor[col], 1);
            adj[pos] = row;
        }
    }
}

// fused weight prep: w_hh -> fp16 row-major; W_gcn -> fp16 transposed [d][k]
__global__ __launch_bounds__(256) void k_wprep(const float* __restrict__ W_gcn, const float* __restrict__ w_hh,
                                               __half* __restrict__ Wt, __half* __restrict__ whh16) {
    int t = blockIdx.x * 256 + threadIdx.x;
    if (t < GATE * DIM) {
        whh16[t] = __float2half(w_hh[t]);
    } else {
        int idx = t - GATE * DIM;
        if (idx < DIM * DIM) {
            int d = idx >> 7, k = idx & 127;
            Wt[idx] = __float2half(W_gcn[k * DIM + d]);
        }
    }
}

// y[n] = (x[n] @ W) * dinv[n] via v_mfma_f32_16x16x32_f16, fp8 e4m3 out.
__global__ __launch_bounds__(256) void k_gemmm(const float* __restrict__ x, const __half* __restrict__ Wt,
                                               const float* __restrict__ dinv, unsigned char* __restrict__ yf8) {
    int tid = threadIdx.x;
    int wt = tid >> 6, lane = tid & 63;
    int lr = lane & 15, kgrp = lane >> 4;
    int rb = blockIdx.x * 64 + wt * 16;

    int rowA = rb + lr;
    if (rowA >= NNODES) rowA = NNODES - 1;
    const float4* x4 = (const float4*)x;

    f32x4 acc[8];
#pragma unroll
    for (int ct = 0; ct < 8; ++ct) acc[ct] = (f32x4){0.f, 0.f, 0.f, 0.f};

#pragma unroll
    for (int c = 0; c < 4; ++c) {
        int kb = c * 32 + kgrp * 8;
        float4 v0 = x4[(size_t)rowA * 32 + (kb >> 2)];
        float4 v1 = x4[(size_t)rowA * 32 + (kb >> 2) + 1];
        half8_t a;
        a[0] = (_Float16)v0.x; a[1] = (_Float16)v0.y; a[2] = (_Float16)v0.z; a[3] = (_Float16)v0.w;
        a[4] = (_Float16)v1.x; a[5] = (_Float16)v1.y; a[6] = (_Float16)v1.z; a[7] = (_Float16)v1.w;
#pragma unroll
        for (int ct = 0; ct < 8; ++ct) {
            int col = ct * 16 + lr;
            half8_t b = *(const half8_t*)(Wt + (size_t)col * DIM + kb);
            acc[ct] = __builtin_amdgcn_mfma_f32_16x16x32_f16(a, b, acc[ct], 0, 0, 0);
        }
    }

    int rowbase = rb + kgrp * 4;
    float dv[4];
    bool ok[4];
#pragma unroll
    for (int r = 0; r < 4; ++r) {
        int row = rowbase + r;
        ok[r] = row < NNODES;
        dv[r] = ok[r] ? dinv[row] : 0.f;
    }
#pragma unroll
    for (int ct = 0; ct < 8; ++ct) {
#pragma unroll
        for (int r = 0; r < 4; ++r) {
            if (ok[r])
                yf8[(size_t)(rowbase + r) * DIM + ct * 16 + lr] = f32_to_fp8(acc[ct][r] * dv[r]);
        }
    }
}

// Fused gather + ReLU + mean-pool partial sums (16 nodes/block, exact grid).
__global__ __launch_bounds__(256) void k_gpool(const int* __restrict__ row_ptr, const int* __restrict__ adj,
                                               const uint2* __restrict__ Y, const float* __restrict__ dinv,
                                               const float* __restrict__ bias, const int* __restrict__ batch,
                                               float* __restrict__ sums) {
    __shared__ float red[16][132];  // +4 pad
    __shared__ int gid[16];
    int tid = threadIdx.x;
    int sl = tid >> 4;   // node slot
    int l = tid & 15;    // 8B chunk (dims 8l..8l+7)
    int n = blockIdx.x * 16 + sl;

    int s = row_ptr[n], e = row_ptr[n + 1];
    float acc[8];
#pragma unroll
    for (int q = 0; q < 8; ++q) acc[q] = 0.f;
    {
        uint2 v = Y[(size_t)n * 16 + l];  // self-loop term
        fp8x4_acc(v.x, acc);
        fp8x4_acc(v.y, acc + 4);
    }
    int i = s;
    for (; i + 3 < e; i += 4) {
        int r0 = adj[i], r1 = adj[i + 1], r2 = adj[i + 2], r3 = adj[i + 3];
        uint2 a0 = Y[(size_t)r0 * 16 + l];
        uint2 a1 = Y[(size_t)r1 * 16 + l];
        uint2 a2 = Y[(size_t)r2 * 16 + l];
        uint2 a3 = Y[(size_t)r3 * 16 + l];
        fp8x4_acc(a0.x, acc); fp8x4_acc(a0.y, acc + 4);
        fp8x4_acc(a1.x, acc); fp8x4_acc(a1.y, acc + 4);
        fp8x4_acc(a2.x, acc); fp8x4_acc(a2.y, acc + 4);
        fp8x4_acc(a3.x, acc); fp8x4_acc(a3.y, acc + 4);
    }
    for (; i < e; ++i) {
        uint2 a0 = Y[(size_t)adj[i] * 16 + l];
        fp8x4_acc(a0.x, acc); fp8x4_acc(a0.y, acc + 4);
    }

    float dv = dinv[n];
#pragma unroll
    for (int q = 0; q < 8; ++q) {
        float v = dv * acc[q] + bias[l * 8 + q];
        red[sl][l * 8 + q] = fmaxf(v, 0.f);
    }
    if (l == 0) gid[sl] = batch[n];
    __syncthreads();

    if (tid < DIM) {
        int d = tid;
        float a = 0.f;
        int g = gid[0];
        for (int s2 = 0; s2 < 16; ++s2) {
            int gs = gid[s2];
            if (gs != g) {
                if (a != 0.f) atomicAdd(&sums[g * DIM + d], a);
                a = 0.f; g = gs;
            }
            a += red[s2][d];
        }
        if (a != 0.f) atomicAdd(&sums[g * DIM + d], a);
    }
}

// xg[t][j] = b_ih[j] + b_hh[j] + pooled[t] . w_ih[j]
__global__ __launch_bounds__(512) void k_xgate(const float* __restrict__ sums, const int* __restrict__ start,
                                               const float* __restrict__ w_ih, const float* __restrict__ b_ih,
                                               const float* __restrict__ b_hh, float* __restrict__ xg) {
    __shared__ float4 p4[DIM / 4];
    int t = blockIdx.x, j = threadIdx.x;
    if (j < DIM) {
        int c = start[t + 1] - start[t];
        float inv = 1.0f / fmaxf((float)c, 1.0f);
        ((float*)p4)[j] = sums[t * DIM + j] * inv;
    }
    __syncthreads();
    const float4* w4 = (const float4*)(w_ih + (size_t)j * DIM);
    float acc = b_ih[j] + b_hh[j];
#pragma unroll
    for (int kk = 0; kk < 32; ++kk) {
        float4 w = w4[kk];
        float4 p = p4[kk];
        acc += w.x * p.x + w.y * p.y + w.z * p.z + w.w * p.w;
    }
    xg[t * GATE + j] = acc;
}

// Sequential LSTM + FC via MFMA, 4 waves, one barrier/step.
// R14 post-mortem: volatile-asm weight loads DID pin 128 VGPRs (68->144)
// but xg was loaded from GLOBAL after the MFMAs -> ~500cy serial stall/step
// (50->63us). Fix: stage ALL of xg (128KB f32) into dynamic LDS once;
// per-step xc is a ~120cy LDS read issued at loop-top and consumed after
// the 32-MFMA block (acc starts at 0; xc added post-MFMA) -> fully hidden.
template <int XLDS>
__global__ __launch_bounds__(256, 1) void k_lstmm(const float* __restrict__ xg, const __half* __restrict__ whh16,
                                                  const float* __restrict__ Wfc, const float* __restrict__ bfc,
                                                  float* __restrict__ out) {
    extern __shared__ char smem[];
    float* xgl = (float*)smem;                         // XLDS only: 64*512 f32
    char* aux = XLDS ? (smem + XL_XG) : smem;
    __half* h2h = (__half*)aux;                        // [2][DIM]
    __half* hsh = (__half*)(aux + 512);                // [NG][DIM]
    int tid = threadIdx.x;
    int wid = tid >> 6, lane = tid & 63;
    int lr = lane & 15, kg = lane >> 4;

    // B-frags via volatile asm: compiler cannot rematerialize -> 128 VGPRs stay resident
    float4 bfr[8][4];
#pragma unroll
    for (int ti = 0; ti < 8; ++ti) {
#pragma unroll
        for (int ks = 0; ks < 4; ++ks) {
            const __half* p = whh16 + (size_t)((wid + 4 * ti) * 16 + lr) * DIM + ks * 32 + kg * 8;
            asm volatile("global_load_dwordx4 %0, %1, off" : "=v"(bfr[ti][ks]) : "v"(p));
        }
    }
    // stage xg -> LDS (does not depend on the loads above)
    if (XLDS) {
        float4* dst = (float4*)xgl;
        const float4* src = (const float4*)xg;
        for (int i = tid; i < NG * GATE / 4; i += 256) dst[i] = src[i];
    }
    asm volatile("s_waitcnt vmcnt(0)" ::: "memory");
    __builtin_amdgcn_sched_barrier(0);

    if (tid < DIM) h2h[tid] = __float2half(0.f);
    float c1 = 0.f, c2 = 0.f;
    int j1 = wid * 16 + lr;        // first h index owned by this lane
    int j2 = (wid + 4) * 16 + lr;  // second
    __syncthreads();

    for (int t = 0; t < NG; ++t) {
        // issue xc reads FIRST (LDS ~120cy, consumed after the MFMA block)
        float xcv[8];
        if (lane < 16) {
#pragma unroll
            for (int ti = 0; ti < 8; ++ti) {
                int idx = t * GATE + (wid + 4 * ti) * 16 + lr;
                xcv[ti] = XLDS ? xgl[idx] : xg[idx];
            }
        }
        const __half* hb = h2h + (t & 1) * DIM;
        half8_t a[4];
#pragma unroll
        for (int ks = 0; ks < 4; ++ks) {
            half8_t av = {};
            if (lr == 0) av = *(const half8_t*)(hb + ks * 32 + kg * 8);
            a[ks] = av;
        }
        f32x4 acc[8];
#pragma unroll
        for (int ti = 0; ti < 8; ++ti) {
            acc[ti] = (f32x4){0.f, 0.f, 0.f, 0.f};
#pragma unroll
            for (int ks = 0; ks < 4; ++ks) {
                union { float4 f; half8_t h; } u; u.f = bfr[ti][ks];
                acc[ti] = __builtin_amdgcn_mfma_f32_16x16x32_f16(a[ks], u.h, acc[ti], 0, 0, 0);
            }
        }
        if (lane < 16) {
            // j1: i=ti0, f=ti2, g=ti4, o=ti6 (reg 0); j2: ti1/3/5/7
            float gi = acc[0][0] + xcv[0], gf = acc[2][0] + xcv[2];
            float gg = acc[4][0] + xcv[4], go = acc[6][0] + xcv[6];
            c1 = sigf(gf) * c1 + sigf(gi) * tanhfast(gg);
            float hn1 = sigf(go) * tanhfast(c1);
            gi = acc[1][0] + xcv[1]; gf = acc[3][0] + xcv[3];
            gg = acc[5][0] + xcv[5]; go = acc[7][0] + xcv[7];
            c2 = sigf(gf) * c2 + sigf(gi) * tanhfast(gg);
            float hn2 = sigf(go) * tanhfast(c2);
            __half h1 = __float2half(hn1), h2 = __float2half(hn2);
            __half* hnb = h2h + ((t + 1) & 1) * DIM;
            hnb[j1] = h1;
            hnb[j2] = h2;
            hsh[t * DIM + j1] = h1;
            hsh[t * DIM + j2] = h2;
        }
        __syncthreads();
    }

    // FC: out[t][cls] = b_fc[cls] + hs[t] . W_fc[cls]
    for (int o = tid; o < NG * 10; o += 256) {
        int t = o / 10, cls = o - t * 10;
        const __half2* hv = (const __half2*)(hsh + t * DIM);
        float acc = bfc[cls];
#pragma unroll
        for (int kk = 0; kk < 64; ++kk) {
            float2 hf = __half22float2(hv[kk]);
            acc += hf.x * Wfc[cls * DIM + 2 * kk] + hf.y * Wfc[cls * DIM + 2 * kk + 1];
        }
        out[o] = acc;
    }
}

extern "C" void kernel_launch(void* const* d_in, const int* in_sizes, int n_in,
                              void* d_out, int out_size, void* d_ws, size_t ws_size,
                              hipStream_t stream) {
    const float* x     = (const float*)d_in[0];
    const int*   ei    = (const int*)d_in[1];
    const int*   batch = (const int*)d_in[2];
    const float* W_gcn = (const float*)d_in[3];
    const float* b_gcn = (const float*)d_in[4];
    const float* w_ih  = (const float*)d_in[5];
    const float* w_hh  = (const float*)d_in[6];
    const float* b_ih  = (const float*)d_in[7];
    const float* b_hh  = (const float*)d_in[8];
    const float* W_fc  = (const float*)d_in[9];
    const float* b_fc  = (const float*)d_in[10];
    float* out = (float*)d_out;

    char* ws = (char*)d_ws;
    unsigned char* yf8 = (unsigned char*)ws;                       // 12.8 MB
    unsigned* pre8 = (unsigned*)(ws + (size_t)NNODES * DIM);       // 12.8 MB (chunk prefixes)
    __half* wt16  = (__half*)(ws + (size_t)NNODES * DIM * 2);      // 32 KB
    unsigned* partial = (unsigned*)(ws + (size_t)NNODES * DIM * 2 + (1 << 16));  // 12.8 MB
    float*  dinv  = (float*)(ws + (size_t)NNODES * DIM * 4);       // 400 KB
    float*  sums  = dinv + 100096;
    float*  xg    = sums + NG * DIM;
    int*    deg   = (int*)(xg + NG * GATE);
    int*    row_ptr = deg + 100096;
    int*    cursor  = row_ptr + 100096;
    int*    adj     = cursor + 100096;      // 6.4 MB
    int*    start   = adj + NEDGES;
    int*    bsum    = start + 128;
    __half* whh16   = (__half*)(bsum + 128);  // 128 KB fp16 LSTM weights (row-major)

    hipMemsetAsync(sums, 0, NG * DIM * sizeof(float), stream);

    bool hist_ok = hipFuncSetAttribute((const void*)k_deghist,
                                       hipFuncAttributeMaxDynamicSharedMemorySize,
                                       HSMEM) == hipSuccess;
    if (hist_ok) {
        k_deghist<<<HG, 1024, HSMEM, stream>>>(ei, partial);
        k_degred2<<<(NNODES / 4 + 255) / 256, 256, 0, stream>>>(partial, pre8, deg, dinv);
    } else {
        hipMemsetAsync(deg, 0, NNODES * sizeof(int), stream);
        k_deg<<<(NEDGES + 255) / 256, 256, 0, stream>>>(ei, deg);
        k_dinv<<<(NNODES + 255) / 256, 256, 0, stream>>>(deg, dinv);
    }
    k_scan1<<<SCAN_NB, 1024, 0, stream>>>(deg, row_ptr, bsum);
    k_scan2<<<1, 128, 0, stream>>>(bsum, row_ptr, batch, start);
    k_scan3<<<SCAN_NB, 1024, 0, stream>>>(row_ptr, bsum, cursor);
    if (hist_ok) {
        for (int p = 0; p < FILL_NPASS; ++p)
            k_fill2<<<HG, 1024, 0, stream>>>(ei, row_ptr, pre8, adj, p * BUCKET);
    } else {
        for (int p = 0; p < FILL_NPASS; ++p)
            k_fillb<<<(NEDGES + 255) / 256, 256, 0, stream>>>(ei, cursor, adj, p * BUCKET);
    }
    k_wprep<<<(GATE * DIM + DIM * DIM + 255) / 256, 256, 0, stream>>>(W_gcn, w_hh, wt16, whh16);
    k_gemmm<<<(NNODES + 63) / 64, 256, 0, stream>>>(x, wt16, dinv, yf8);
    k_gpool<<<NNODES / 16, 256, 0, stream>>>(row_ptr, adj, (const uint2*)yf8, dinv, b_gcn, batch, sums);
    k_xgate<<<NG, 512, 0, stream>>>(sums, start, w_ih, b_ih, b_hh, xg);

    bool xlds_ok = hipFuncSetAttribute((const void*)k_lstmm<1>,
                                       hipFuncAttributeMaxDynamicSharedMemorySize,
                                       XL_SMEM) == hipSuccess;
    if (xlds_ok)
        k_lstmm<1><<<1, 256, XL_SMEM, stream>>>(xg, whh16, W_fc, b_fc, out);
    else
        k_lstmm<0><<<1, 256, XL_AUX, stream>>>(xg, whh16, W_fc, b_fc, out);
}

// Round 16
// 237.339 us; speedup vs baseline: 1.0469x; 1.0469x over previous
//
#include <hip/hip_runtime.h>
#include <hip/hip_fp16.h>
#include <math.h>

#if __has_builtin(__builtin_amdgcn_cvt_pk_f32_fp8) && __has_builtin(__builtin_amdgcn_cvt_pk_fp8_f32)
#define HAS_FP8_CVT 1
#else
#include <hip/hip_fp8.h>
#endif

#define NNODES 100000
#define NEDGES 1600000
#define DIM 128
#define NG 64
#define GATE 512
#define SCAN_NB 98  // ceil(NNODES / 1024)
#define FILL_NPASS 4
#define BUCKET ((NNODES + FILL_NPASS - 1) / FILL_NPASS)  // 25000

// degree histogram / counting-sort offsets
#define HG 128           // edge chunks (12500 edges each)
#define HW 25024         // u32 words per partial (4 packed u8 cols each)
#define HSMEM (HW * 4)   // 100096 B dynamic LDS for k_deghist

// k_lstmm dynamic LDS: xg staged f32 + h double-buffer + h history
#define XL_XG   131072                        // 64*512*4
#define XL_AUX  (512 + 16384)                 // h2h[2][128] half + hsh[64][128] half
#define XL_SMEM (XL_XG + XL_AUX)              // 147968 <= 160K

typedef _Float16 half8_t __attribute__((ext_vector_type(8)));
typedef float f32x4 __attribute__((ext_vector_type(4)));
typedef float f32x2_t __attribute__((ext_vector_type(2)));

// fp8 e4m3 HW converters (encode/decode self-consistent on gfx950)
__device__ __forceinline__ unsigned char f32_to_fp8(float v) {
#ifdef HAS_FP8_CVT
    return (unsigned char)(__builtin_amdgcn_cvt_pk_fp8_f32(v, v, 0, false) & 0xFF);
#else
    __hip_fp8_e4m3 h(v); return h.__x;
#endif
}
__device__ __forceinline__ void fp8x4_acc(unsigned w, float* acc) {
#ifdef HAS_FP8_CVT
    f32x2_t lo = __builtin_amdgcn_cvt_pk_f32_fp8((int)w, false);
    f32x2_t hi = __builtin_amdgcn_cvt_pk_f32_fp8((int)w, true);
    acc[0] += lo[0]; acc[1] += lo[1]; acc[2] += hi[0]; acc[3] += hi[1];
#else
    __hip_fp8_e4m3 h;
#pragma unroll
    for (int q = 0; q < 4; ++q) { h.__x = (w >> (8 * q)) & 0xFF; acc[q] += (float)h; }
#endif
}

// fast sigmoid/tanh: v_exp_f32 + v_rcp_f32 (absmax headroom is ~100x)
__device__ __forceinline__ float sigf(float x) {
    return __builtin_amdgcn_rcpf(1.0f + __expf(-x));
}
__device__ __forceinline__ float tanhfast(float x) {
    float e = __expf(2.0f * x);
    return 1.0f - 2.0f * __builtin_amdgcn_rcpf(e + 1.0f);
}

// ---- degree: per-edge-chunk LDS u8-packed histogram, NO global atomics ----
__global__ __launch_bounds__(1024) void k_deghist(const int* __restrict__ ei, unsigned* __restrict__ partial) {
    extern __shared__ unsigned hist[];  // HW words
    int tid = threadIdx.x;
    for (int i = tid; i < HW; i += 1024) hist[i] = 0u;
    __syncthreads();
    int e0 = blockIdx.x * (NEDGES / HG);
    int e1 = e0 + (NEDGES / HG);
    for (int e = e0 + tid; e < e1; e += 1024) {
        int col = ei[NEDGES + e];
        atomicAdd(&hist[col >> 2], 1u << ((col & 3) * 8));
    }
    __syncthreads();
    unsigned* dst = partial + (size_t)blockIdx.x * HW;
    for (int i = tid; i < HW; i += 1024) dst[i] = hist[i];
}

// fallback if 100KB dynamic LDS unavailable: plain atomic count
__global__ __launch_bounds__(256) void k_deg(const int* __restrict__ ei, int* __restrict__ deg) {
    int e = blockIdx.x * 256 + threadIdx.x;
    if (e < NEDGES) atomicAdd(&deg[ei[NEDGES + e]], 1);
}

// sum HG partials -> deg + dinv, and emit per-chunk exclusive prefix pre8
__global__ __launch_bounds__(256) void k_degred2(const unsigned* __restrict__ partial, unsigned* __restrict__ pre8,
                                                 int* __restrict__ deg, float* __restrict__ dinv) {
    int w = blockIdx.x * 256 + threadIdx.x;  // packed word = 4 cols
    if (w >= NNODES / 4) return;
    unsigned s = 0;
    for (int b = 0; b < HG; ++b) {
        pre8[(size_t)b * HW + w] = s;        // exclusive prefix before chunk b
        s += partial[(size_t)b * HW + w];
    }
    int4 d;
    d.x = s & 255; d.y = (s >> 8) & 255; d.z = (s >> 16) & 255; d.w = (int)(s >> 24);
    ((int4*)deg)[w] = d;
    float4 dv;
    dv.x = rsqrtf((float)d.x + 1.f);
    dv.y = rsqrtf((float)d.y + 1.f);
    dv.z = rsqrtf((float)d.z + 1.f);
    dv.w = rsqrtf((float)d.w + 1.f);
    ((float4*)dinv)[w] = dv;
}

// dinv for the atomic fallback path
__global__ __launch_bounds__(256) void k_dinv(const int* __restrict__ deg, float* __restrict__ dinv) {
    int n = blockIdx.x * 256 + threadIdx.x;
    if (n < NNODES) dinv[n] = rsqrtf((float)deg[n] + 1.0f);
}

// stage 1: per-block exclusive scan of deg; block sums out
__global__ __launch_bounds__(1024) void k_scan1(const int* __restrict__ deg, int* __restrict__ row_ptr,
                                                int* __restrict__ bsum) {
    __shared__ int ls[1024];
    int tid = threadIdx.x;
    int n = blockIdx.x * 1024 + tid;
    int v = (n < NNODES) ? deg[n] : 0;
    ls[tid] = v;
    __syncthreads();
    for (int off = 1; off < 1024; off <<= 1) {
        int t = (tid >= off) ? ls[tid - off] : 0;
        __syncthreads();
        ls[tid] += t;
        __syncthreads();
    }
    if (n < NNODES) row_ptr[n] = ls[tid] - v;  // exclusive within block
    if (tid == 1023) bsum[blockIdx.x] = ls[1023];
}

// stage 2: exclusive scan of block sums + graph segment bounds (batch sorted)
__global__ __launch_bounds__(128) void k_scan2(int* __restrict__ bsum, int* __restrict__ row_ptr,
                                               const int* __restrict__ batch, int* __restrict__ start) {
    __shared__ int ls[128];
    int tid = threadIdx.x;
    int v = (tid < SCAN_NB) ? bsum[tid] : 0;
    ls[tid] = v;
    __syncthreads();
    for (int off = 1; off < 128; off <<= 1) {
        int t = (tid >= off) ? ls[tid - off] : 0;
        __syncthreads();
        ls[tid] += t;
        __syncthreads();
    }
    if (tid < SCAN_NB) bsum[tid] = ls[tid] - v;  // exclusive block offsets
    if (tid == 127) row_ptr[NNODES] = ls[127];
    if (tid <= NG) {
        int lo = 0, hi = NNODES;
        while (lo < hi) {
            int mid = (lo + hi) >> 1;
            if (batch[mid] < tid) lo = mid + 1; else hi = mid;
        }
        start[tid] = lo;
    }
}

// stage 3: add block offsets; init cursor = row_ptr (cursor used by fallback fill only)
__global__ __launch_bounds__(1024) void k_scan3(int* __restrict__ row_ptr, const int* __restrict__ bsum,
                                                int* __restrict__ cursor) {
    int n = blockIdx.x * 1024 + threadIdx.x;
    if (n < NNODES) {
        int rp = row_ptr[n] + bsum[blockIdx.x];
        row_ptr[n] = rp;
        cursor[n] = rp;
    }
}

// Atomic-free CSR fill (counting sort): slot = row_ptr + chunk prefix + LDS local
__global__ __launch_bounds__(1024) void k_fill2(const int* __restrict__ ei, const int* __restrict__ row_ptr,
                                                const unsigned* __restrict__ pre8, int* __restrict__ adj, int b0) {
    __shared__ unsigned lh[BUCKET / 4];  // 25 KB
    int tid = threadIdx.x;
    for (int i = tid; i < BUCKET / 4; i += 1024) lh[i] = 0u;
    __syncthreads();
    const unsigned* myPre = pre8 + (size_t)blockIdx.x * HW;
    int e0 = blockIdx.x * (NEDGES / HG);
    int e1 = e0 + (NEDGES / HG);
    for (int e = e0 + tid; e < e1; e += 1024) {
        int col = ei[NEDGES + e];
        if (col >= b0 && col < b0 + BUCKET) {
            int row = ei[e];
            int lc = col - b0;
            unsigned old = atomicAdd(&lh[lc >> 2], 1u << ((lc & 3) * 8));
            int local = (old >> ((lc & 3) * 8)) & 0xFF;
            int base = row_ptr[col] + (int)((myPre[col >> 2] >> ((col & 3) * 8)) & 0xFF);
            adj[base + local] = row;
        }
    }
}

// fallback: cursor-based fill with temporal bucketing
__global__ __launch_bounds__(256) void k_fillb(const int* __restrict__ ei, int* __restrict__ cursor,
                                               int* __restrict__ adj, int b0) {
    int e = blockIdx.x * 256 + threadIdx.x;
    if (e < NEDGES) {
        int col = ei[NEDGES + e];
        if (col >= b0 && col < b0 + BUCKET) {
            int row = ei[e];
            int pos = atomicAdd(&cursor[col], 1);
            adj[pos] = row;
        }
    }
}

// fused weight prep: w_hh -> fp16 row-major; W_gcn -> fp16 transposed [d][k]
__global__ __launch_bounds__(256) void k_wprep(const float* __restrict__ W_gcn, const float* __restrict__ w_hh,
                                               __half* __restrict__ Wt, __half* __restrict__ whh16) {
    int t = blockIdx.x * 256 + threadIdx.x;
    if (t < GATE * DIM) {
        whh16[t] = __float2half(w_hh[t]);
    } else {
        int idx = t - GATE * DIM;
        if (idx < DIM * DIM) {
            int d = idx >> 7, k = idx & 127;
            Wt[idx] = __float2half(W_gcn[k * DIM + d]);
        }
    }
}

// y[n] = (x[n] @ W) * dinv[n] via v_mfma_f32_16x16x32_f16, fp8 e4m3 out.
__global__ __launch_bounds__(256) void k_gemmm(const float* __restrict__ x, const __half* __restrict__ Wt,
                                               const float* __restrict__ dinv, unsigned char* __restrict__ yf8) {
    int tid = threadIdx.x;
    int wt = tid >> 6, lane = tid & 63;
    int lr = lane & 15, kgrp = lane >> 4;
    int rb = blockIdx.x * 64 + wt * 16;

    int rowA = rb + lr;
    if (rowA >= NNODES) rowA = NNODES - 1;
    const float4* x4 = (const float4*)x;

    f32x4 acc[8];
#pragma unroll
    for (int ct = 0; ct < 8; ++ct) acc[ct] = (f32x4){0.f, 0.f, 0.f, 0.f};

#pragma unroll
    for (int c = 0; c < 4; ++c) {
        int kb = c * 32 + kgrp * 8;
        float4 v0 = x4[(size_t)rowA * 32 + (kb >> 2)];
        float4 v1 = x4[(size_t)rowA * 32 + (kb >> 2) + 1];
        half8_t a;
        a[0] = (_Float16)v0.x; a[1] = (_Float16)v0.y; a[2] = (_Float16)v0.z; a[3] = (_Float16)v0.w;
        a[4] = (_Float16)v1.x; a[5] = (_Float16)v1.y; a[6] = (_Float16)v1.z; a[7] = (_Float16)v1.w;
#pragma unroll
        for (int ct = 0; ct < 8; ++ct) {
            int col = ct * 16 + lr;
            half8_t b = *(const half8_t*)(Wt + (size_t)col * DIM + kb);
            acc[ct] = __builtin_amdgcn_mfma_f32_16x16x32_f16(a, b, acc[ct], 0, 0, 0);
        }
    }

    int rowbase = rb + kgrp * 4;
    float dv[4];
    bool ok[4];
#pragma unroll
    for (int r = 0; r < 4; ++r) {
        int row = rowbase + r;
        ok[r] = row < NNODES;
        dv[r] = ok[r] ? dinv[row] : 0.f;
    }
#pragma unroll
    for (int ct = 0; ct < 8; ++ct) {
#pragma unroll
        for (int r = 0; r < 4; ++r) {
            if (ok[r])
                yf8[(size_t)(rowbase + r) * DIM + ct * 16 + lr] = f32_to_fp8(acc[ct][r] * dv[r]);
        }
    }
}

// Fused gather + ReLU + mean-pool partial sums (16 nodes/block, exact grid).
__global__ __launch_bounds__(256) void k_gpool(const int* __restrict__ row_ptr, const int* __restrict__ adj,
                                               const uint2* __restrict__ Y, const float* __restrict__ dinv,
                                               const float* __restrict__ bias, const int* __restrict__ batch,
                                               float* __restrict__ sums) {
    __shared__ float red[16][132];  // +4 pad
    __shared__ int gid[16];
    int tid = threadIdx.x;
    int sl = tid >> 4;   // node slot
    int l = tid & 15;    // 8B chunk (dims 8l..8l+7)
    int n = blockIdx.x * 16 + sl;

    int s = row_ptr[n], e = row_ptr[n + 1];
    float acc[8];
#pragma unroll
    for (int q = 0; q < 8; ++q) acc[q] = 0.f;
    {
        uint2 v = Y[(size_t)n * 16 + l];  // self-loop term
        fp8x4_acc(v.x, acc);
        fp8x4_acc(v.y, acc + 4);
    }
    int i = s;
    for (; i + 3 < e; i += 4) {
        int r0 = adj[i], r1 = adj[i + 1], r2 = adj[i + 2], r3 = adj[i + 3];
        uint2 a0 = Y[(size_t)r0 * 16 + l];
        uint2 a1 = Y[(size_t)r1 * 16 + l];
        uint2 a2 = Y[(size_t)r2 * 16 + l];
        uint2 a3 = Y[(size_t)r3 * 16 + l];
        fp8x4_acc(a0.x, acc); fp8x4_acc(a0.y, acc + 4);
        fp8x4_acc(a1.x, acc); fp8x4_acc(a1.y, acc + 4);
        fp8x4_acc(a2.x, acc); fp8x4_acc(a2.y, acc + 4);
        fp8x4_acc(a3.x, acc); fp8x4_acc(a3.y, acc + 4);
    }
    for (; i < e; ++i) {
        uint2 a0 = Y[(size_t)adj[i] * 16 + l];
        fp8x4_acc(a0.x, acc); fp8x4_acc(a0.y, acc + 4);
    }

    float dv = dinv[n];
#pragma unroll
    for (int q = 0; q < 8; ++q) {
        float v = dv * acc[q] + bias[l * 8 + q];
        red[sl][l * 8 + q] = fmaxf(v, 0.f);
    }
    if (l == 0) gid[sl] = batch[n];
    __syncthreads();

    if (tid < DIM) {
        int d = tid;
        float a = 0.f;
        int g = gid[0];
        for (int s2 = 0; s2 < 16; ++s2) {
            int gs = gid[s2];
            if (gs != g) {
                if (a != 0.f) atomicAdd(&sums[g * DIM + d], a);
                a = 0.f; g = gs;
            }
            a += red[s2][d];
        }
        if (a != 0.f) atomicAdd(&sums[g * DIM + d], a);
    }
}

// xg[t][j] = b_ih[j] + b_hh[j] + pooled[t] . w_ih[j]
__global__ __launch_bounds__(512) void k_xgate(const float* __restrict__ sums, const int* __restrict__ start,
                                               const float* __restrict__ w_ih, const float* __restrict__ b_ih,
                                               const float* __restrict__ b_hh, float* __restrict__ xg) {
    __shared__ float4 p4[DIM / 4];
    int t = blockIdx.x, j = threadIdx.x;
    if (j < DIM) {
        int c = start[t + 1] - start[t];
        float inv = 1.0f / fmaxf((float)c, 1.0f);
        ((float*)p4)[j] = sums[t * DIM + j] * inv;
    }
    __syncthreads();
    const float4* w4 = (const float4*)(w_ih + (size_t)j * DIM);
    float acc = b_ih[j] + b_hh[j];
#pragma unroll
    for (int kk = 0; kk < 32; ++kk) {
        float4 w = w4[kk];
        float4 p = p4[kk];
        acc += w.x * p.x + w.y * p.y + w.z * p.z + w.w * p.w;
    }
    xg[t * GATE + j] = acc;
}

// Sequential LSTM + FC via MFMA: 8 waves (2/SIMD -> stalls overlap),
// volatile-asm-pinned weights (64 VGPR/thread of B-frags), one barrier/step.
// R13 (8w, streaming weights) = 50us; R14/15 (4w, resident weights) = 62us:
// 1 wave/SIMD exposed every stall. This combines resident weights WITH
// 2 waves/SIMD. ct = wid + 8*ti (ti = gate 0..3): all four gates of
// h[j] in wave j>>4, lane j&15, reg 0 -> activation register-local,
// one h/lane, c in register; h double-buffered so one barrier suffices.
template <int XLDS>
__global__ __launch_bounds__(512, 2) void k_lstmm(const float* __restrict__ xg, const __half* __restrict__ whh16,
                                                  const float* __restrict__ Wfc, const float* __restrict__ bfc,
                                                  float* __restrict__ out) {
    extern __shared__ char smem[];
    float* xgl = (float*)smem;                         // XLDS only: 64*512 f32
    char* aux = XLDS ? (smem + XL_XG) : smem;
    __half* h2h = (__half*)aux;                        // [2][DIM]
    __half* hsh = (__half*)(aux + 512);                // [NG][DIM]
    int tid = threadIdx.x;
    int wid = tid >> 6, lane = tid & 63;
    int lr = lane & 15, kg = lane >> 4;

    // B-frags via volatile asm (cannot be rematerialized -> stays resident):
    // ti = gate 0..3 -> ct = wid + 8*ti; col = ct*16+lr; k = ks*32+kg*8
    float4 bfr[4][4];
#pragma unroll
    for (int ti = 0; ti < 4; ++ti) {
#pragma unroll
        for (int ks = 0; ks < 4; ++ks) {
            const __half* p = whh16 + (size_t)((wid + 8 * ti) * 16 + lr) * DIM + ks * 32 + kg * 8;
            asm volatile("global_load_dwordx4 %0, %1, off" : "=v"(bfr[ti][ks]) : "v"(p));
        }
    }
    // stage xg -> LDS (independent of the weight loads)
    if (XLDS) {
        float4* dst = (float4*)xgl;
        const float4* src = (const float4*)xg;
        for (int i = tid; i < NG * GATE / 4; i += 512) dst[i] = src[i];
    }
    asm volatile("s_waitcnt vmcnt(0)" ::: "memory");
    __builtin_amdgcn_sched_barrier(0);

    if (tid < DIM) h2h[tid] = __float2half(0.f);
    float c = 0.f;
    int j = wid * 16 + lr;  // the single h index owned by this lane (lanes<16)
    __syncthreads();

    for (int t = 0; t < NG; ++t) {
        float xcv[4];
        if (lane < 16) {
#pragma unroll
            for (int ti = 0; ti < 4; ++ti) {
                int idx = t * GATE + (wid + 8 * ti) * 16 + lr;
                xcv[ti] = XLDS ? xgl[idx] : xg[idx];
            }
        }
        const __half* hb = h2h + (t & 1) * DIM;
        half8_t a[4];
#pragma unroll
        for (int ks = 0; ks < 4; ++ks) {
            half8_t av = {};
            if (lr == 0) av = *(const half8_t*)(hb + ks * 32 + kg * 8);
            a[ks] = av;
        }
        f32x4 acc[4];
#pragma unroll
        for (int ti = 0; ti < 4; ++ti) {
            acc[ti] = (f32x4){0.f, 0.f, 0.f, 0.f};
#pragma unroll
            for (int ks = 0; ks < 4; ++ks) {
                union { float4 f; half8_t h; } u; u.f = bfr[ti][ks];
                acc[ti] = __builtin_amdgcn_mfma_f32_16x16x32_f16(a[ks], u.h, acc[ti], 0, 0, 0);
            }
        }
        if (lane < 16) {
            // gate order i,f,g,o = ti 0..3; row 0 reg 0 for lanes 0-15
            float gi = acc[0][0] + xcv[0], gf = acc[1][0] + xcv[1];
            float gg = acc[2][0] + xcv[2], go = acc[3][0] + xcv[3];
            c = sigf(gf) * c + sigf(gi) * tanhfast(gg);
            float hn = sigf(go) * tanhfast(c);
            __half h1 = __float2half(hn);
            h2h[((t + 1) & 1) * DIM + j] = h1;
            hsh[t * DIM + j] = h1;
        }
        __syncthreads();
    }

    // FC: out[t][cls] = b_fc[cls] + hs[t] . W_fc[cls]
    for (int o = tid; o < NG * 10; o += 512) {
        int t = o / 10, cls = o - t * 10;
        const __half2* hv = (const __half2*)(hsh + t * DIM);
        float acc = bfc[cls];
#pragma unroll
        for (int kk = 0; kk < 64; ++kk) {
            float2 hf = __half22float2(hv[kk]);
            acc += hf.x * Wfc[cls * DIM + 2 * kk] + hf.y * Wfc[cls * DIM + 2 * kk + 1];
        }
        out[o] = acc;
    }
}

extern "C" void kernel_launch(void* const* d_in, const int* in_sizes, int n_in,
                              void* d_out, int out_size, void* d_ws, size_t ws_size,
                              hipStream_t stream) {
    const float* x     = (const float*)d_in[0];
    const int*   ei    = (const int*)d_in[1];
    const int*   batch = (const int*)d_in[2];
    const float* W_gcn = (const float*)d_in[3];
    const float* b_gcn = (const float*)d_in[4];
    const float* w_ih  = (const float*)d_in[5];
    const float* w_hh  = (const float*)d_in[6];
    const float* b_ih  = (const float*)d_in[7];
    const float* b_hh  = (const float*)d_in[8];
    const float* W_fc  = (const float*)d_in[9];
    const float* b_fc  = (const float*)d_in[10];
    float* out = (float*)d_out;

    char* ws = (char*)d_ws;
    unsigned char* yf8 = (unsigned char*)ws;                       // 12.8 MB
    unsigned* pre8 = (unsigned*)(ws + (size_t)NNODES * DIM);       // 12.8 MB (chunk prefixes)
    __half* wt16  = (__half*)(ws + (size_t)NNODES * DIM * 2);      // 32 KB
    unsigned* partial = (unsigned*)(ws + (size_t)NNODES * DIM * 2 + (1 << 16));  // 12.8 MB
    float*  dinv  = (float*)(ws + (size_t)NNODES * DIM * 4);       // 400 KB
    float*  sums  = dinv + 100096;
    float*  xg    = sums + NG * DIM;
    int*    deg   = (int*)(xg + NG * GATE);
    int*    row_ptr = deg + 100096;
    int*    cursor  = row_ptr + 100096;
    int*    adj     = cursor + 100096;      // 6.4 MB
    int*    start   = adj + NEDGES;
    int*    bsum    = start + 128;
    __half* whh16   = (__half*)(bsum + 128);  // 128 KB fp16 LSTM weights (row-major)

    hipMemsetAsync(sums, 0, NG * DIM * sizeof(float), stream);

    bool hist_ok = hipFuncSetAttribute((const void*)k_deghist,
                                       hipFuncAttributeMaxDynamicSharedMemorySize,
                                       HSMEM) == hipSuccess;
    if (hist_ok) {
        k_deghist<<<HG, 1024, HSMEM, stream>>>(ei, partial);
        k_degred2<<<(NNODES / 4 + 255) / 256, 256, 0, stream>>>(partial, pre8, deg, dinv);
    } else {
        hipMemsetAsync(deg, 0, NNODES * sizeof(int), stream);
        k_deg<<<(NEDGES + 255) / 256, 256, 0, stream>>>(ei, deg);
        k_dinv<<<(NNODES + 255) / 256, 256, 0, stream>>>(deg, dinv);
    }
    k_scan1<<<SCAN_NB, 1024, 0, stream>>>(deg, row_ptr, bsum);
    k_scan2<<<1, 128, 0, stream>>>(bsum, row_ptr, batch, start);
    k_scan3<<<SCAN_NB, 1024, 0, stream>>>(row_ptr, bsum, cursor);
    if (hist_ok) {
        for (int p = 0; p < FILL_NPASS; ++p)
            k_fill2<<<HG, 1024, 0, stream>>>(ei, row_ptr, pre8, adj, p * BUCKET);
    } else {
        for (int p = 0; p < FILL_NPASS; ++p)
            k_fillb<<<(NEDGES + 255) / 256, 256, 0, stream>>>(ei, cursor, adj, p * BUCKET);
    }
    k_wprep<<<(GATE * DIM + DIM * DIM + 255) / 256, 256, 0, stream>>>(W_gcn, w_hh, wt16, whh16);
    k_gemmm<<<(NNODES + 63) / 64, 256, 0, stream>>>(x, wt16, dinv, yf8);
    k_gpool<<<NNODES / 16, 256, 0, stream>>>(row_ptr, adj, (const uint2*)yf8, dinv, b_gcn, batch, sums);
    k_xgate<<<NG, 512, 0, stream>>>(sums, start, w_ih, b_ih, b_hh, xg);

    bool xlds_ok = hipFuncSetAttribute((const void*)k_lstmm<1>,
                                       hipFuncAttributeMaxDynamicSharedMemorySize,
                                       XL_SMEM) == hipSuccess;
    if (xlds_ok)
        k_lstmm<1><<<1, 512, XL_SMEM, stream>>>(xg, whh16, W_fc, b_fc, out);
    else
        k_lstmm<0><<<1, 512, XL_AUX, stream>>>(xg, whh16, W_fc, b_fc, out);
}

// Round 18
// 233.867 us; speedup vs baseline: 1.0624x; 1.0148x over previous
//
#include <hip/hip_runtime.h>
#include <hip/hip_fp16.h>
#include <math.h>

#if __has_builtin(__builtin_amdgcn_cvt_pk_f32_fp8) && __has_builtin(__builtin_amdgcn_cvt_pk_fp8_f32)
#define HAS_FP8_CVT 1
#else
#include <hip/hip_fp8.h>
#endif

#define NNODES 100000
#define NEDGES 1600000
#define DIM 128
#define NG 64
#define GATE 512
#define SCAN_NB 98  // ceil(NNODES / 1024)
#define FILL_NPASS 2
#define BUCKET 50000  // cols per fill pass; 50KB LDS histogram

// degree histogram / counting-sort offsets
#define HG 128           // edge chunks (12500 edges each)
#define HW 25024         // u32 words per partial (4 packed u8 cols each)
#define HSMEM (HW * 4)   // 100096 B dynamic LDS for k_deghist

// workspace byte offsets (NON-overlapping; R17 crash was pre8/wt16 overlap:
// HG*HW*4 = 12,812,288 > NNODES*DIM = 12,800,000)
#define OFF_PRE8  ((size_t)NNODES * DIM)   // 12,800,000
#define OFF_WT16  ((size_t)25620000)       // > OFF_PRE8 + 12,812,288 = 25,612,288
#define OFF_PART  ((size_t)25700000)       // > OFF_WT16 + 65,536; ends 38.5M < 51.2M
#define OFF_DINV  ((size_t)NNODES * DIM * 4)  // 51,200,000 (unchanged)

// k_lstmm dynamic LDS: xg staged f32 + h double-buffer + h history
#define XL_XG   131072                        // 64*512*4
#define XL_AUX  (512 + 16384)                 // h2h[2][128] half + hsh[64][128] half
#define XL_SMEM (XL_XG + XL_AUX)              // 147968 <= 160K

typedef _Float16 half8_t __attribute__((ext_vector_type(8)));
typedef float f32x4 __attribute__((ext_vector_type(4)));
typedef float f32x2_t __attribute__((ext_vector_type(2)));

// fp8 e4m3 HW converters (encode/decode self-consistent on gfx950)
__device__ __forceinline__ unsigned char f32_to_fp8(float v) {
#ifdef HAS_FP8_CVT
    return (unsigned char)(__builtin_amdgcn_cvt_pk_fp8_f32(v, v, 0, false) & 0xFF);
#else
    __hip_fp8_e4m3 h(v); return h.__x;
#endif
}
__device__ __forceinline__ void fp8x4_acc(unsigned w, float* acc) {
#ifdef HAS_FP8_CVT
    f32x2_t lo = __builtin_amdgcn_cvt_pk_f32_fp8((int)w, false);
    f32x2_t hi = __builtin_amdgcn_cvt_pk_f32_fp8((int)w, true);
    acc[0] += lo[0]; acc[1] += lo[1]; acc[2] += hi[0]; acc[3] += hi[1];
#else
    __hip_fp8_e4m3 h;
#pragma unroll
    for (int q = 0; q < 4; ++q) { h.__x = (w >> (8 * q)) & 0xFF; acc[q] += (float)h; }
#endif
}

// fast sigmoid/tanh: v_exp_f32 + v_rcp_f32 (absmax headroom is ~100x)
__device__ __forceinline__ float sigf(float x) {
    return __builtin_amdgcn_rcpf(1.0f + __expf(-x));
}
__device__ __forceinline__ float tanhfast(float x) {
    float e = __expf(2.0f * x);
    return 1.0f - 2.0f * __builtin_amdgcn_rcpf(e + 1.0f);
}

// ---- degree: per-edge-chunk LDS u8-packed histogram, NO global atomics ----
__global__ __launch_bounds__(1024) void k_deghist(const int* __restrict__ ei, unsigned* __restrict__ partial) {
    extern __shared__ unsigned hist[];  // HW words
    int tid = threadIdx.x;
    for (int i = tid; i < HW; i += 1024) hist[i] = 0u;
    __syncthreads();
    int e0 = blockIdx.x * (NEDGES / HG);
    int e1 = e0 + (NEDGES / HG);
    for (int e = e0 + tid; e < e1; e += 1024) {
        int col = ei[NEDGES + e];
        atomicAdd(&hist[col >> 2], 1u << ((col & 3) * 8));
    }
    __syncthreads();
    unsigned* dst = partial + (size_t)blockIdx.x * HW;
    for (int i = tid; i < HW; i += 1024) dst[i] = hist[i];
}

// fallback if 100KB dynamic LDS unavailable: plain atomic count
__global__ __launch_bounds__(256) void k_deg(const int* __restrict__ ei, int* __restrict__ deg) {
    int e = blockIdx.x * 256 + threadIdx.x;
    if (e < NEDGES) atomicAdd(&deg[ei[NEDGES + e]], 1);
}

// sum HG partials -> deg + dinv, and emit per-chunk exclusive prefix pre8
__global__ __launch_bounds__(256) void k_degred2(const unsigned* __restrict__ partial, unsigned* __restrict__ pre8,
                                                 int* __restrict__ deg, float* __restrict__ dinv) {
    int w = blockIdx.x * 256 + threadIdx.x;  // packed word = 4 cols
    if (w >= NNODES / 4) return;
    unsigned s = 0;
    for (int b = 0; b < HG; ++b) {
        pre8[(size_t)b * HW + w] = s;        // exclusive prefix before chunk b
        s += partial[(size_t)b * HW + w];
    }
    int4 d;
    d.x = s & 255; d.y = (s >> 8) & 255; d.z = (s >> 16) & 255; d.w = (int)(s >> 24);
    ((int4*)deg)[w] = d;
    float4 dv;
    dv.x = rsqrtf((float)d.x + 1.f);
    dv.y = rsqrtf((float)d.y + 1.f);
    dv.z = rsqrtf((float)d.z + 1.f);
    dv.w = rsqrtf((float)d.w + 1.f);
    ((float4*)dinv)[w] = dv;
}

// dinv for the atomic fallback path
__global__ __launch_bounds__(256) void k_dinv(const int* __restrict__ deg, float* __restrict__ dinv) {
    int n = blockIdx.x * 256 + threadIdx.x;
    if (n < NNODES) dinv[n] = rsqrtf((float)deg[n] + 1.0f);
}

// stage 1: per-block exclusive scan of deg; block sums out
__global__ __launch_bounds__(1024) void k_scan1(const int* __restrict__ deg, int* __restrict__ row_ptr,
                                                int* __restrict__ bsum) {
    __shared__ int ls[1024];
    int tid = threadIdx.x;
    int n = blockIdx.x * 1024 + tid;
    int v = (n < NNODES) ? deg[n] : 0;
    ls[tid] = v;
    __syncthreads();
    for (int off = 1; off < 1024; off <<= 1) {
        int t = (tid >= off) ? ls[tid - off] : 0;
        __syncthreads();
        ls[tid] += t;
        __syncthreads();
    }
    if (n < NNODES) row_ptr[n] = ls[tid] - v;  // exclusive within block
    if (tid == 1023) bsum[blockIdx.x] = ls[1023];
}

// stage 2: exclusive scan of block sums + graph segment bounds (batch sorted)
__global__ __launch_bounds__(128) void k_scan2(int* __restrict__ bsum, int* __restrict__ row_ptr,
                                               const int* __restrict__ batch, int* __restrict__ start) {
    __shared__ int ls[128];
    int tid = threadIdx.x;
    int v = (tid < SCAN_NB) ? bsum[tid] : 0;
    ls[tid] = v;
    __syncthreads();
    for (int off = 1; off < 128; off <<= 1) {
        int t = (tid >= off) ? ls[tid - off] : 0;
        __syncthreads();
        ls[tid] += t;
        __syncthreads();
    }
    if (tid < SCAN_NB) bsum[tid] = ls[tid] - v;  // exclusive block offsets
    if (tid == 127) row_ptr[NNODES] = ls[127];
    if (tid <= NG) {
        int lo = 0, hi = NNODES;
        while (lo < hi) {
            int mid = (lo + hi) >> 1;
            if (batch[mid] < tid) lo = mid + 1; else hi = mid;
        }
        start[tid] = lo;
    }
}

// stage 3: add block offsets; init cursor; ALSO fold in weight prep
// (98 blocks x 1024 = 100352 threads >= 81920 wprep elements)
__global__ __launch_bounds__(1024) void k_scan3(int* __restrict__ row_ptr, const int* __restrict__ bsum,
                                                int* __restrict__ cursor,
                                                const float* __restrict__ W_gcn, const float* __restrict__ w_hh,
                                                __half* __restrict__ Wt, __half* __restrict__ whh16) {
    int n = blockIdx.x * 1024 + threadIdx.x;
    if (n < NNODES) {
        int rp = row_ptr[n] + bsum[blockIdx.x];
        row_ptr[n] = rp;
        cursor[n] = rp;
    }
    // weight prep: first GATE*DIM -> whh16; next DIM*DIM -> Wt (transposed)
    if (n < GATE * DIM) {
        whh16[n] = __float2half(w_hh[n]);
    } else {
        int idx = n - GATE * DIM;
        if (idx < DIM * DIM) {
            int d = idx >> 7, k = idx & 127;
            Wt[idx] = __float2half(W_gcn[k * DIM + d]);
        }
    }
}

// Atomic-free CSR fill (counting sort): slot = row_ptr + chunk prefix + LDS local.
// 2 passes x 50K-col buckets (50KB LDS): halves redundant col re-reads vs 4 passes.
__global__ __launch_bounds__(1024) void k_fill2(const int* __restrict__ ei, const int* __restrict__ row_ptr,
                                                const unsigned* __restrict__ pre8, int* __restrict__ adj, int b0) {
    __shared__ unsigned lh[BUCKET / 4];  // 50 KB
    int tid = threadIdx.x;
    for (int i = tid; i < BUCKET / 4; i += 1024) lh[i] = 0u;
    __syncthreads();
    const unsigned* myPre = pre8 + (size_t)blockIdx.x * HW;
    int e0 = blockIdx.x * (NEDGES / HG);
    int e1 = e0 + (NEDGES / HG);
    for (int e = e0 + tid; e < e1; e += 1024) {
        int col = ei[NEDGES + e];
        if (col >= b0 && col < b0 + BUCKET) {
            int row = ei[e];
            int lc = col - b0;
            unsigned old = atomicAdd(&lh[lc >> 2], 1u << ((lc & 3) * 8));
            int local = (old >> ((lc & 3) * 8)) & 0xFF;
            int base = row_ptr[col] + (int)((myPre[col >> 2] >> ((col & 3) * 8)) & 0xFF);
            adj[base + local] = row;
        }
    }
}

// fallback: cursor-based fill with temporal bucketing
__global__ __launch_bounds__(256) void k_fillb(const int* __restrict__ ei, int* __restrict__ cursor,
                                               int* __restrict__ adj, int b0) {
    int e = blockIdx.x * 256 + threadIdx.x;
    if (e < NEDGES) {
        int col = ei[NEDGES + e];
        if (col >= b0 && col < b0 + BUCKET) {
            int row = ei[e];
            int pos = atomicAdd(&cursor[col], 1);
            adj[pos] = row;
        }
    }
}

// fallback weight prep (used only with atomic deg path)
__global__ __launch_bounds__(256) void k_wprep(const float* __restrict__ W_gcn, const float* __restrict__ w_hh,
                                               __half* __restrict__ Wt, __half* __restrict__ whh16) {
    int t = blockIdx.x * 256 + threadIdx.x;
    if (t < GATE * DIM) {
        whh16[t] = __float2half(w_hh[t]);
    } else {
        int idx = t - GATE * DIM;
        if (idx < DIM * DIM) {
            int d = idx >> 7, k = idx & 127;
            Wt[idx] = __float2half(W_gcn[k * DIM + d]);
        }
    }
}

// y[n] = (x[n] @ W) * dinv[n] via v_mfma_f32_16x16x32_f16, fp8 e4m3 out.
__global__ __launch_bounds__(256) void k_gemmm(const float* __restrict__ x, const __half* __restrict__ Wt,
                                               const float* __restrict__ dinv, unsigned char* __restrict__ yf8) {
    int tid = threadIdx.x;
    int wt = tid >> 6, lane = tid & 63;
    int lr = lane & 15, kgrp = lane >> 4;
    int rb = blockIdx.x * 64 + wt * 16;

    int rowA = rb + lr;
    if (rowA >= NNODES) rowA = NNODES - 1;
    const float4* x4 = (const float4*)x;

    f32x4 acc[8];
#pragma unroll
    for (int ct = 0; ct < 8; ++ct) acc[ct] = (f32x4){0.f, 0.f, 0.f, 0.f};

#pragma unroll
    for (int c = 0; c < 4; ++c) {
        int kb = c * 32 + kgrp * 8;
        float4 v0 = x4[(size_t)rowA * 32 + (kb >> 2)];
        float4 v1 = x4[(size_t)rowA * 32 + (kb >> 2) + 1];
        half8_t a;
        a[0] = (_Float16)v0.x; a[1] = (_Float16)v0.y; a[2] = (_Float16)v0.z; a[3] = (_Float16)v0.w;
        a[4] = (_Float16)v1.x; a[5] = (_Float16)v1.y; a[6] = (_Float16)v1.z; a[7] = (_Float16)v1.w;
#pragma unroll
        for (int ct = 0; ct < 8; ++ct) {
            int col = ct * 16 + lr;
            half8_t b = *(const half8_t*)(Wt + (size_t)col * DIM + kb);
            acc[ct] = __builtin_amdgcn_mfma_f32_16x16x32_f16(a, b, acc[ct], 0, 0, 0);
        }
    }

    int rowbase = rb + kgrp * 4;
    float dv[4];
    bool ok[4];
#pragma unroll
    for (int r = 0; r < 4; ++r) {
        int row = rowbase + r;
        ok[r] = row < NNODES;
        dv[r] = ok[r] ? dinv[row] : 0.f;
    }
#pragma unroll
    for (int ct = 0; ct < 8; ++ct) {
#pragma unroll
        for (int r = 0; r < 4; ++r) {
            if (ok[r])
                yf8[(size_t)(rowbase + r) * DIM + ct * 16 + lr] = f32_to_fp8(acc[ct][r] * dv[r]);
        }
    }
}

// Fused gather + ReLU + mean-pool partial sums (16 nodes/block, exact grid).
__global__ __launch_bounds__(256) void k_gpool(const int* __restrict__ row_ptr, const int* __restrict__ adj,
                                               const uint2* __restrict__ Y, const float* __restrict__ dinv,
                                               const float* __restrict__ bias, const int* __restrict__ batch,
                                               float* __restrict__ sums) {
    __shared__ float red[16][132];  // +4 pad
    __shared__ int gid[16];
    int tid = threadIdx.x;
    int sl = tid >> 4;   // node slot
    int l = tid & 15;    // 8B chunk (dims 8l..8l+7)
    int n = blockIdx.x * 16 + sl;

    int s = row_ptr[n], e = row_ptr[n + 1];
    float acc[8];
#pragma unroll
    for (int q = 0; q < 8; ++q) acc[q] = 0.f;
    {
        uint2 v = Y[(size_t)n * 16 + l];  // self-loop term
        fp8x4_acc(v.x, acc);
        fp8x4_acc(v.y, acc + 4);
    }
    int i = s;
    for (; i + 3 < e; i += 4) {
        int r0 = adj[i], r1 = adj[i + 1], r2 = adj[i + 2], r3 = adj[i + 3];
        uint2 a0 = Y[(size_t)r0 * 16 + l];
        uint2 a1 = Y[(size_t)r1 * 16 + l];
        uint2 a2 = Y[(size_t)r2 * 16 + l];
        uint2 a3 = Y[(size_t)r3 * 16 + l];
        fp8x4_acc(a0.x, acc); fp8x4_acc(a0.y, acc + 4);
        fp8x4_acc(a1.x, acc); fp8x4_acc(a1.y, acc + 4);
        fp8x4_acc(a2.x, acc); fp8x4_acc(a2.y, acc + 4);
        fp8x4_acc(a3.x, acc); fp8x4_acc(a3.y, acc + 4);
    }
    for (; i < e; ++i) {
        uint2 a0 = Y[(size_t)adj[i] * 16 + l];
        fp8x4_acc(a0.x, acc); fp8x4_acc(a0.y, acc + 4);
    }

    float dv = dinv[n];
#pragma unroll
    for (int q = 0; q < 8; ++q) {
        float v = dv * acc[q] + bias[l * 8 + q];
        red[sl][l * 8 + q] = fmaxf(v, 0.f);
    }
    if (l == 0) gid[sl] = batch[n];
    __syncthreads();

    if (tid < DIM) {
        int d = tid;
        float a = 0.f;
        int g = gid[0];
        for (int s2 = 0; s2 < 16; ++s2) {
            int gs = gid[s2];
            if (gs != g) {
                if (a != 0.f) atomicAdd(&sums[g * DIM + d], a);
                a = 0.f; g = gs;
            }
            a += red[s2][d];
        }
        if (a != 0.f) atomicAdd(&sums[g * DIM + d], a);
    }
}

// xg[t][j] = b_ih[j] + b_hh[j] + pooled[t] . w_ih[j]
__global__ __launch_bounds__(512) void k_xgate(const float* __restrict__ sums, const int* __restrict__ start,
                                               const float* __restrict__ w_ih, const float* __restrict__ b_ih,
                                               const float* __restrict__ b_hh, float* __restrict__ xg) {
    __shared__ float4 p4[DIM / 4];
    int t = blockIdx.x, j = threadIdx.x;
    if (j < DIM) {
        int c = start[t + 1] - start[t];
        float inv = 1.0f / fmaxf((float)c, 1.0f);
        ((float*)p4)[j] = sums[t * DIM + j] * inv;
    }
    __syncthreads();
    const float4* w4 = (const float4*)(w_ih + (size_t)j * DIM);
    float acc = b_ih[j] + b_hh[j];
#pragma unroll
    for (int kk = 0; kk < 32; ++kk) {
        float4 w = w4[kk];
        float4 p = p4[kk];
        acc += w.x * p.x + w.y * p.y + w.z * p.z + w.w * p.w;
    }
    xg[t * GATE + j] = acc;
}

// Sequential LSTM + FC via MFMA: 8 waves (2/SIMD), pinned weights, one
// barrier/step; gate tile = two independent 2-MFMA chains (halved dep depth).
template <int XLDS>
__global__ __launch_bounds__(512, 2) void k_lstmm(const float* __restrict__ xg, const __half* __restrict__ whh16,
                                                  const float* __restrict__ Wfc, const float* __restrict__ bfc,
                                                  float* __restrict__ out) {
    extern __shared__ char smem[];
    float* xgl = (float*)smem;                         // XLDS only: 64*512 f32
    char* aux = XLDS ? (smem + XL_XG) : smem;
    __half* h2h = (__half*)aux;                        // [2][DIM]
    __half* hsh = (__half*)(aux + 512);                // [NG][DIM]
    int tid = threadIdx.x;
    int wid = tid >> 6, lane = tid & 63;
    int lr = lane & 15, kg = lane >> 4;

    // B-frags via volatile asm (cannot be rematerialized -> stays resident)
    float4 bfr[4][4];
#pragma unroll
    for (int ti = 0; ti < 4; ++ti) {
#pragma unroll
        for (int ks = 0; ks < 4; ++ks) {
            const __half* p = whh16 + (size_t)((wid + 8 * ti) * 16 + lr) * DIM + ks * 32 + kg * 8;
            asm volatile("global_load_dwordx4 %0, %1, off" : "=v"(bfr[ti][ks]) : "v"(p));
        }
    }
    if (XLDS) {
        float4* dst = (float4*)xgl;
        const float4* src = (const float4*)xg;
        for (int i = tid; i < NG * GATE / 4; i += 512) dst[i] = src[i];
    }
    asm volatile("s_waitcnt vmcnt(0)" ::: "memory");
    __builtin_amdgcn_sched_barrier(0);

    if (tid < DIM) h2h[tid] = __float2half(0.f);
    float c = 0.f;
    int j = wid * 16 + lr;  // the single h index owned by this lane (lanes<16)
    __syncthreads();

    for (int t = 0; t < NG; ++t) {
        float xcv[4];
        if (lane < 16) {
#pragma unroll
            for (int ti = 0; ti < 4; ++ti) {
                int idx = t * GATE + (wid + 8 * ti) * 16 + lr;
                xcv[ti] = XLDS ? xgl[idx] : xg[idx];
            }
        }
        const __half* hb = h2h + (t & 1) * DIM;
        half8_t a[4];
#pragma unroll
        for (int ks = 0; ks < 4; ++ks) {
            half8_t av = {};
            if (lr == 0) av = *(const half8_t*)(hb + ks * 32 + kg * 8);
            a[ks] = av;
        }
        float gate[4];
#pragma unroll
        for (int ti = 0; ti < 4; ++ti) {
            union { float4 f; half8_t h; } u0, u1, u2, u3;
            u0.f = bfr[ti][0]; u1.f = bfr[ti][1]; u2.f = bfr[ti][2]; u3.f = bfr[ti][3];
            f32x4 acc0 = (f32x4){0.f, 0.f, 0.f, 0.f};
            f32x4 acc1 = (f32x4){0.f, 0.f, 0.f, 0.f};
            acc0 = __builtin_amdgcn_mfma_f32_16x16x32_f16(a[0], u0.h, acc0, 0, 0, 0);
            acc1 = __builtin_amdgcn_mfma_f32_16x16x32_f16(a[2], u2.h, acc1, 0, 0, 0);
            acc0 = __builtin_amdgcn_mfma_f32_16x16x32_f16(a[1], u1.h, acc0, 0, 0, 0);
            acc1 = __builtin_amdgcn_mfma_f32_16x16x32_f16(a[3], u3.h, acc1, 0, 0, 0);
            gate[ti] = acc0[0] + acc1[0];
        }
        if (lane < 16) {
            float gi = gate[0] + xcv[0], gf = gate[1] + xcv[1];
            float gg = gate[2] + xcv[2], go = gate[3] + xcv[3];
            c = sigf(gf) * c + sigf(gi) * tanhfast(gg);
            float hn = sigf(go) * tanhfast(c);
            __half h1 = __float2half(hn);
            h2h[((t + 1) & 1) * DIM + j] = h1;
            hsh[t * DIM + j] = h1;
        }
        __syncthreads();
    }

    // FC: out[t][cls] = b_fc[cls] + hs[t] . W_fc[cls]
    for (int o = tid; o < NG * 10; o += 512) {
        int t = o / 10, cls = o - t * 10;
        const __half2* hv = (const __half2*)(hsh + t * DIM);
        float acc = bfc[cls];
#pragma unroll
        for (int kk = 0; kk < 64; ++kk) {
            float2 hf = __half22float2(hv[kk]);
            acc += hf.x * Wfc[cls * DIM + 2 * kk] + hf.y * Wfc[cls * DIM + 2 * kk + 1];
        }
        out[o] = acc;
    }
}

extern "C" void kernel_launch(void* const* d_in, const int* in_sizes, int n_in,
                              void* d_out, int out_size, void* d_ws, size_t ws_size,
                              hipStream_t stream) {
    const float* x     = (const float*)d_in[0];
    const int*   ei    = (const int*)d_in[1];
    const int*   batch = (const int*)d_in[2];
    const float* W_gcn = (const float*)d_in[3];
    const float* b_gcn = (const float*)d_in[4];
    const float* w_ih  = (const float*)d_in[5];
    const float* w_hh  = (const float*)d_in[6];
    const float* b_ih  = (const float*)d_in[7];
    const float* b_hh  = (const float*)d_in[8];
    const float* W_fc  = (const float*)d_in[9];
    const float* b_fc  = (const float*)d_in[10];
    float* out = (float*)d_out;

    char* ws = (char*)d_ws;
    unsigned char* yf8 = (unsigned char*)ws;                 // 12.8 MB
    unsigned* pre8    = (unsigned*)(ws + OFF_PRE8);          // 12,812,288 B
    __half*  wt16     = (__half*)(ws + OFF_WT16);            // 32 KB
    unsigned* partial = (unsigned*)(ws + OFF_PART);          // 12,812,288 B (ends 38.5M)
    float*  dinv  = (float*)(ws + OFF_DINV);                 // 400 KB @ 51.2M
    float*  sums  = dinv + 100096;
    float*  xg    = sums + NG * DIM;
    int*    deg   = (int*)(xg + NG * GATE);
    int*    row_ptr = deg + 100096;
    int*    cursor  = row_ptr + 100096;
    int*    adj     = cursor + 100096;      // 6.4 MB
    int*    start   = adj + NEDGES;
    int*    bsum    = start + 128;
    __half* whh16   = (__half*)(bsum + 128);  // 128 KB fp16 LSTM weights (row-major)

    hipMemsetAsync(sums, 0, NG * DIM * sizeof(float), stream);

    bool hist_ok = hipFuncSetAttribute((const void*)k_deghist,
                                       hipFuncAttributeMaxDynamicSharedMemorySize,
                                       HSMEM) == hipSuccess;
    if (hist_ok) {
        k_deghist<<<HG, 1024, HSMEM, stream>>>(ei, partial);
        k_degred2<<<(NNODES / 4 + 255) / 256, 256, 0, stream>>>(partial, pre8, deg, dinv);
    } else {
        hipMemsetAsync(deg, 0, NNODES * sizeof(int), stream);
        k_deg<<<(NEDGES + 255) / 256, 256, 0, stream>>>(ei, deg);
        k_dinv<<<(NNODES + 255) / 256, 256, 0, stream>>>(deg, dinv);
    }
    k_scan1<<<SCAN_NB, 1024, 0, stream>>>(deg, row_ptr, bsum);
    k_scan2<<<1, 128, 0, stream>>>(bsum, row_ptr, batch, start);
    k_scan3<<<SCAN_NB, 1024, 0, stream>>>(row_ptr, bsum, cursor, W_gcn, w_hh, wt16, whh16);
    if (hist_ok) {
        for (int p = 0; p < FILL_NPASS; ++p)
            k_fill2<<<HG, 1024, 0, stream>>>(ei, row_ptr, pre8, adj, p * BUCKET);
    } else {
        k_wprep<<<(GATE * DIM + DIM * DIM + 255) / 256, 256, 0, stream>>>(W_gcn, w_hh, wt16, whh16);
        for (int p = 0; p < FILL_NPASS; ++p)
            k_fillb<<<(NEDGES + 255) / 256, 256, 0, stream>>>(ei, cursor, adj, p * BUCKET);
    }
    k_gemmm<<<(NNODES + 63) / 64, 256, 0, stream>>>(x, wt16, dinv, yf8);
    k_gpool<<<NNODES / 16, 256, 0, stream>>>(row_ptr, adj, (const uint2*)yf8, dinv, b_gcn, batch, sums);
    k_xgate<<<NG, 512, 0, stream>>>(sums, start, w_ih, b_ih, b_hh, xg);

    bool xlds_ok = hipFuncSetAttribute((const void*)k_lstmm<1>,
                                       hipFuncAttributeMaxDynamicSharedMemorySize,
                                       XL_SMEM) == hipSuccess;
    if (xlds_ok)
        k_lstmm<1><<<1, 512, XL_SMEM, stream>>>(xg, whh16, W_fc, b_fc, out);
    else
        k_lstmm<0><<<1, 512, XL_AUX, stream>>>(xg, whh16, W_fc, b_fc, out);
}